// Round 1
// baseline (755.638 us; speedup 1.0000x reference)
//
#include <hip/hip_runtime.h>
#include <cstdint>
#include <cstddef>

#define NCLS 4
#define NB   8
#define NC   64
#define NP   65536
#define EPSN 1e-12f

// ws layout (floats)
#define WS_Y   0     // [4][8][64] normalized sampled feature vectors
#define WS_ERR 2048  // [4][8] error flags (class absent)
#define WS_ACC 2080  // [4][8] squared-diff accumulators

__device__ __forceinline__ uint32_t rotl32(uint32_t v, uint32_t d) {
  return (v << d) | (v >> (32u - d));
}

// JAX threefry2x32, 20 rounds.
__device__ __forceinline__ void threefry2x32(uint32_t k0, uint32_t k1,
                                             uint32_t& x0, uint32_t& x1) {
  uint32_t ks2 = k0 ^ k1 ^ 0x1BD11BDAu;
  const uint32_t rA[4] = {13u, 15u, 26u, 6u};
  const uint32_t rB[4] = {17u, 29u, 16u, 24u};
  x0 += k0; x1 += k1;
#pragma unroll
  for (int i = 0; i < 4; ++i) { x0 += x1; x1 = rotl32(x1, rA[i]); x1 ^= x0; }
  x0 += k1; x1 += ks2 + 1u;
#pragma unroll
  for (int i = 0; i < 4; ++i) { x0 += x1; x1 = rotl32(x1, rB[i]); x1 ^= x0; }
  x0 += ks2; x1 += k0 + 2u;
#pragma unroll
  for (int i = 0; i < 4; ++i) { x0 += x1; x1 = rotl32(x1, rA[i]); x1 ^= x0; }
  x0 += k0; x1 += k1 + 3u;
#pragma unroll
  for (int i = 0; i < 4; ++i) { x0 += x1; x1 = rotl32(x1, rB[i]); x1 ^= x0; }
  x0 += k1; x1 += ks2 + 4u;
#pragma unroll
  for (int i = 0; i < 4; ++i) { x0 += x1; x1 = rotl32(x1, rA[i]); x1 ^= x0; }
  x0 += ks2; x1 += k0 + 5u;
}

// u = jax.random.uniform(split(key(42),4)[k], (8,))[b]
// (jax_threefry_partitionable=True semantics: split -> full 2x32 output at
//  counter (0,k); 32-bit bits -> out0^out1 at counter (0,b).)
__device__ __forceinline__ float jax_uniform_u(int k, int b) {
  uint32_t kk0, kk1;
  {
    uint32_t x0 = 0u, x1 = (uint32_t)k;
    threefry2x32(0u, 42u, x0, x1);
    kk0 = x0; kk1 = x1;
  }
  uint32_t x0 = 0u, x1 = (uint32_t)b;
  threefry2x32(kk0, kk1, x0, x1);
  uint32_t bits = x0 ^ x1;
  union { uint32_t u; float f; } c;
  c.u = (bits >> 9) | 0x3f800000u;
  float f = c.f - 1.0f;
  return f < 0.f ? 0.f : f;
}

// grid = 32 blocks (k = bi>>3, b = bi&7), 256 threads.
// Each thread owns 256 contiguous pixels; builds match bitmask in registers.
__global__ __launch_bounds__(256) void sample_kernel(
    const float* __restrict__ f1_0, const float* __restrict__ f1_1,
    const float* __restrict__ f1_2, const float* __restrict__ f1_3,
    const int* __restrict__ t1, float* __restrict__ ws) {
  __shared__ int s_cnt[256];
  __shared__ int s_info[4];  // err, seg, lrank, idx
  const int k = blockIdx.x >> 3;
  const int b = blockIdx.x & 7;
  const int tid = threadIdx.x;
  const int base = tid * 256;
  const int4* tb4 = (const int4*)(t1 + (size_t)b * NP + base);

  uint32_t bits[8];
  int cnt = 0;
#pragma unroll
  for (int w = 0; w < 8; ++w) {
    uint32_t m = 0u;
#pragma unroll
    for (int q = 0; q < 8; ++q) {
      int4 v = tb4[w * 8 + q];
      m |= (v.x == k ? 1u : 0u) << (q * 4 + 0);
      m |= (v.y == k ? 1u : 0u) << (q * 4 + 1);
      m |= (v.z == k ? 1u : 0u) << (q * 4 + 2);
      m |= (v.w == k ? 1u : 0u) << (q * 4 + 3);
    }
    bits[w] = m;
    cnt += __popc(m);
  }
  s_cnt[tid] = cnt;
  __syncthreads();

  if (tid == 0) {
    int total = 0;
    for (int t = 0; t < 256; ++t) total += s_cnt[t];
    const int err = (total == 0) ? 1 : 0;
    const float u = jax_uniform_u(k, b);
    const float fcnt = (float)(total > 0 ? total : 1);
    int r = (int)floorf(u * fcnt);
    int rmax = total - 1; if (rmax < 0) rmax = 0;
    if (r > rmax) r = rmax;
    int seg = 0, pre = 0;
    if (!err) {
      int acc = 0;
      for (int t = 0; t < 256; ++t) {
        int c2 = s_cnt[t];
        if (acc + c2 > r) { seg = t; pre = acc; break; }
        acc += c2;
      }
    }
    s_info[0] = err;
    s_info[1] = seg;
    s_info[2] = r - pre;  // local rank within segment
  }
  __syncthreads();

  const int err = s_info[0];
  if (tid == s_info[1]) {
    int idx = 0;
    if (!err) {
      int lrank = s_info[2];
      int w = 0;
      for (;;) {
        int pc = __popc(bits[w]);
        if (lrank < pc) break;
        lrank -= pc;
        ++w;
      }
      uint32_t m = bits[w];
      for (int j = 0; j < lrank; ++j) m &= (m - 1u);
      int bitpos = __ffs(m) - 1;
      idx = base + w * 32 + bitpos;
    }
    s_info[3] = idx;
  }
  __syncthreads();

  const int idx = s_info[3];
  if (tid < 64) {
    const float* f1 = (k == 0) ? f1_0 : (k == 1) ? f1_1 : (k == 2) ? f1_2 : f1_3;
    float v = f1[((size_t)b * NC + tid) * NP + idx];
    float s = v * v;
#pragma unroll
    for (int off = 32; off; off >>= 1) s += __shfl_xor(s, off, 64);
    float nrm = sqrtf(s);
    float scale = err ? 0.f : (1.f / fmaxf(nrm, EPSN));
    ws[WS_Y + (size_t)blockIdx.x * 64 + tid] = v * scale;
    if (tid == 0) {
      ws[WS_ERR + blockIdx.x] = (float)err;
      ws[WS_ACC + blockIdx.x] = 0.f;  // zero accumulator for loss_kernel
    }
  }
}

// grid = 4*8*64 = 2048 blocks, 256 threads; each thread owns 4 pixels.
__global__ __launch_bounds__(256) void loss_kernel(
    const float* __restrict__ f2_0, const float* __restrict__ f2_1,
    const float* __restrict__ f2_2, const float* __restrict__ f2_3,
    const int* __restrict__ t2, float* __restrict__ ws) {
  __shared__ float s_y[64];
  __shared__ float s_red[4];
  const int bi = blockIdx.x;
  const int chunk = bi & 63;
  const int b = (bi >> 6) & 7;
  const int k = bi >> 9;
  const int tid = threadIdx.x;

  if (tid < 64) s_y[tid] = ws[WS_Y + (size_t)(k * 8 + b) * 64 + tid];
  __syncthreads();

  const float* f2 = (k == 0) ? f2_0 : (k == 1) ? f2_1 : (k == 2) ? f2_2 : f2_3;
  const int p0 = chunk * 1024 + tid * 4;
  const size_t pbase = (size_t)b * NC * NP + p0;

  float4 sq = make_float4(0.f, 0.f, 0.f, 0.f);
  float4 dt = make_float4(0.f, 0.f, 0.f, 0.f);
#pragma unroll 8
  for (int c = 0; c < NC; ++c) {
    const float4 v = *(const float4*)(f2 + pbase + (size_t)c * NP);
    const float yh = s_y[c];
    sq.x += v.x * v.x; sq.y += v.y * v.y;
    sq.z += v.z * v.z; sq.w += v.w * v.w;
    dt.x += v.x * yh;  dt.y += v.y * yh;
    dt.z += v.z * yh;  dt.w += v.w * yh;
  }

  const int4 tv = *(const int4*)(t2 + (size_t)b * NP + p0);
  float local = 0.f;
  {
    float inner = dt.x / fmaxf(sqrtf(sq.x), EPSN);
    float d = inner - ((tv.x == k) ? 1.f : -1.f);
    local += d * d;
  }
  {
    float inner = dt.y / fmaxf(sqrtf(sq.y), EPSN);
    float d = inner - ((tv.y == k) ? 1.f : -1.f);
    local += d * d;
  }
  {
    float inner = dt.z / fmaxf(sqrtf(sq.z), EPSN);
    float d = inner - ((tv.z == k) ? 1.f : -1.f);
    local += d * d;
  }
  {
    float inner = dt.w / fmaxf(sqrtf(sq.w), EPSN);
    float d = inner - ((tv.w == k) ? 1.f : -1.f);
    local += d * d;
  }

#pragma unroll
  for (int off = 32; off; off >>= 1) local += __shfl_xor(local, off, 64);
  const int wave = tid >> 6;
  if ((tid & 63) == 0) s_red[wave] = local;
  __syncthreads();
  if (tid == 0) {
    float s = s_red[0] + s_red[1] + s_red[2] + s_red[3];
    atomicAdd(&ws[WS_ACC + k * 8 + b], s);
  }
}

__global__ void final_kernel(const float* __restrict__ ws, float* __restrict__ out) {
  if (threadIdx.x == 0 && blockIdx.x == 0) {
    float l4 = 0.f;
    for (int k = 0; k < 4; ++k) {
      float lk = 0.f;
      for (int b = 0; b < 8; ++b) {
        float acc = ws[WS_ACC + k * 8 + b];
        float err = ws[WS_ERR + k * 8 + b];
        lk += acc * (1.f - err);
      }
      lk = lk / (float)NP / 8.f;
      out[k] = lk;
      l4 += lk;
    }
    out[4] = l4 * 0.25f;
  }
}

extern "C" void kernel_launch(void* const* d_in, const int* in_sizes, int n_in,
                              void* d_out, int out_size, void* d_ws, size_t ws_size,
                              hipStream_t stream) {
  // Identify inputs by size: 8 big tensors (f1 x4 then f2 x4 in order),
  // 2 int target maps (t1 then t2). Robust to dict-vs-signature ordering
  // since relative order within each size class is the same.
  const float* f1[4] = {nullptr, nullptr, nullptr, nullptr};
  const float* f2[4] = {nullptr, nullptr, nullptr, nullptr};
  const int* tt[2] = {nullptr, nullptr};
  int nbig = 0, nsmall = 0;
  const int BIG = NB * NC * NP;   // 33554432
  const int SMALL = NB * NP;      // 524288
  for (int i = 0; i < n_in; ++i) {
    if (in_sizes[i] == BIG) {
      if (nbig < 4) f1[nbig] = (const float*)d_in[i];
      else if (nbig < 8) f2[nbig - 4] = (const float*)d_in[i];
      ++nbig;
    } else if (in_sizes[i] == SMALL) {
      if (nsmall < 2) tt[nsmall] = (const int*)d_in[i];
      ++nsmall;
    }
  }

  float* ws = (float*)d_ws;
  float* out = (float*)d_out;

  sample_kernel<<<32, 256, 0, stream>>>(f1[0], f1[1], f1[2], f1[3], tt[0], ws);
  loss_kernel<<<2048, 256, 0, stream>>>(f2[0], f2[1], f2[2], f2[3], tt[1], ws);
  final_kernel<<<1, 64, 0, stream>>>(ws, out);
}